// Round 6
// baseline (123.842 us; speedup 1.0000x reference)
//
#include <hip/hip_runtime.h>

// PlaceCellNetwork — 50 fixed-point Jacobi iterations, per-row independent.
//
// R6: f16 K-pair packing with f32 accumulation via v_dot2_f32_f16.
//
// R3/R5 post-mortem: fp32 scalar plateaus at ~71 us; m07's measured fp32-FMA
// ceiling (103 TF ~ 3 cyc/wave-inst effective) says that IS the fp32 wall.
// Switch currency: v_dot2_f32_f16 does 2 f16 MACs + f32 accumulate per lane
// per inst at full VALU rate. Inner loop: 10 outputs x 5 dot2 = 50 insts
// + 10 max + 15 repack = 75 insts/iter vs 110 fp32 (and 2x MACs per inst).
//
// Precision: accumulation stays f32; state is quantized to f16 (RNE) once
// per iteration -> steady-state noise ~1e-3*|z|, absmax ~0.05-0.15 vs
// threshold 0.318. Coefficients f16-rounded once (~0.5% on G, negligible).
//
// Iteration (z-space, identical to reference up to rounding; Y_j = rd_j*z_j):
//   z_j <- max( sum_k G[k][j]*z_k + c_j , 0 )
//   G[j][j] = (1-dt)*rd_j ; G[k][j] = -dt*rd_k*M_kj ; rd_j = 1/(lbd2+M_jj)
//   c_j = dt*(Wx_j - b_j) - lbd1
// K packed in pairs: Gp[m][j] = (G[2m][j], G[2m+1][j]) half2, zp[m] half2.

typedef _Float16 h2 __attribute__((ext_vector_type(2)));

constexpr int IN_DIM  = 5;
constexpr int OUT_DIM = 10;
constexpr int ITERS   = 50;
constexpr int KP      = OUT_DIM / 2;   // 5 k-pairs

__global__ __launch_bounds__(256, 1) void pcn_kernel(
    const float* __restrict__ X,    // [n, 5]
    const float* __restrict__ W,    // [10, 5]
    const float* __restrict__ Mg,   // [10, 10]
    const float* __restrict__ b,    // [10]
    float* __restrict__ out,        // [n, 10]
    int n)
{
    const float DT = 0.05f, LBD1 = 0.005f, LBD2 = 0.005f;

    int i = blockIdx.x * blockDim.x + threadIdx.x;
    if (i >= n) return;

    // ---- uniform tables (prologue, once) ----
    float rd[OUT_DIM];
#pragma unroll
    for (int j = 0; j < OUT_DIM; ++j)
        rd[j] = __builtin_amdgcn_rcpf(LBD2 + Mg[j * OUT_DIM + j]); // 1ulp: fine

    float Gf[OUT_DIM][OUT_DIM];     // G[k][j]
#pragma unroll
    for (int k = 0; k < OUT_DIM; ++k) {
        float f = -DT * rd[k];
#pragma unroll
        for (int j = 0; j < OUT_DIM; ++j)
            Gf[k][j] = (j == k) ? (1.0f - DT) * rd[j]
                                : f * Mg[k * OUT_DIM + j];
    }
    // pack along k: Gp[m][j] = (G[2m][j], G[2m+1][j])
    h2 Gp[KP][OUT_DIM];
#pragma unroll
    for (int m = 0; m < KP; ++m)
#pragma unroll
        for (int j = 0; j < OUT_DIM; ++j)
            Gp[m][j] = h2{(_Float16)Gf[2 * m][j], (_Float16)Gf[2 * m + 1][j]};

    // ---- per-row constant c (f32) ----
    float x[IN_DIM];
#pragma unroll
    for (int d = 0; d < IN_DIM; ++d) x[d] = X[(size_t)i * IN_DIM + d];
    float c[OUT_DIM];
#pragma unroll
    for (int j = 0; j < OUT_DIM; ++j) {
        float s = -b[j];
#pragma unroll
        for (int d = 0; d < IN_DIM; ++d)
            s = fmaf(x[d], W[j * IN_DIM + d], s);
        c[j] = fmaf(DT, s, -LBD1);
    }

    // ---- 50 iterations: 50 dot2 + 10 max + 15 repack per iter ----
    h2 zp[KP];
#pragma unroll
    for (int m = 0; m < KP; ++m) zp[m] = h2{(_Float16)0.0f, (_Float16)0.0f};

#pragma unroll 1
    for (int it = 0; it < ITERS; ++it) {
        float s[OUT_DIM];
#pragma unroll
        for (int j = 0; j < OUT_DIM; ++j) {
            float acc = c[j];
#pragma unroll
            for (int m = 0; m < KP; ++m)
                acc = __builtin_amdgcn_fdot2(zp[m], Gp[m][j], acc, false);
            s[j] = fmaxf(acc, 0.0f);
        }
#pragma unroll
        for (int m = 0; m < KP; ++m)
            zp[m] = h2{(_Float16)s[2 * m], (_Float16)s[2 * m + 1]}; // RNE cvt
    }

    // ---- epilogue: Y = rd .* z, contiguous 40B/row ----
#pragma unroll
    for (int m = 0; m < KP; ++m) {
        out[(size_t)i * OUT_DIM + 2 * m]     = rd[2 * m]     * (float)zp[m].x;
        out[(size_t)i * OUT_DIM + 2 * m + 1] = rd[2 * m + 1] * (float)zp[m].y;
    }
}

extern "C" void kernel_launch(void* const* d_in, const int* in_sizes, int n_in,
                              void* d_out, int out_size, void* d_ws, size_t ws_size,
                              hipStream_t stream) {
    const float* X = (const float*)d_in[0];
    const float* W = (const float*)d_in[1];
    const float* M = (const float*)d_in[2];
    const float* b = (const float*)d_in[3];
    float* out = (float*)d_out;

    int n = in_sizes[0] / IN_DIM;   // 500000 rows
    int block = 256;
    int grid = (n + block - 1) / block;
    pcn_kernel<<<grid, block, 0, stream>>>(X, W, M, b, out, n);
}

// Round 7
// 121.923 us; speedup vs baseline: 1.0157x; 1.0157x over previous
//
#include <hip/hip_runtime.h>
#include <stdint.h>

// PlaceCellNetwork — 50 fixed-point Jacobi iterations, per-row independent.
//
// R7: coefficient table in SGPRs via setup-kernel + uniform s_load,
//     consumed by v_dot2_f32_f16 (1 SGPR src per VOP3P inst — legal).
//
// Why: R3/R5/R6 all show the compiler refuses to keep a VALU-computed
// wave-uniform table VGPR-resident (VGPR_Count 72/72/44) — the pre-RA remat
// stage re-derives entries in-loop (~2x instr bloat). R4 showed 90 f32
// coefficients overflow the ~100-SGPR file. Synthesis: pack the table to
// 50 half2 words (fits SGPRs), build it ONCE in a tiny setup kernel into
// d_ws, and have the main kernel read it via uniform const loads -> s_load.
// SGPR values from loads are trivially resident; nothing to remat.
//
// Iteration (z-space; Y_j = rd_j * z_j):
//   z_j <- max( sum_k G[k][j]*z_k + c_j , 0 )
//   G[j][j] = (1-dt)*rd_j ; G[k][j] = -dt*rd_k*M_kj ; rd_j = 1/(lbd2+M_jj)
//   c_j = dt*(Wx_j - b_j) - lbd1
// K packed in h2 pairs; f32 accumulation (state quantized f16-RNE once/iter;
// measured absmax 0.0625 in R6 with identical numerics).
//
// Inner loop: 50 v_dot2_f32_f16 + 10 v_cvt_f16_f32 + 5 v_pack_b32_f16
//           + 5 v_pk_max_f16 = 70 insts/iter. ~3800 inst/thread
//           -> ~58k cyc/SIMD -> ~24 us ideal, ~30 us expected.

typedef _Float16 h2 __attribute__((ext_vector_type(2)));

constexpr int IN_DIM  = 5;
constexpr int OUT_DIM = 10;
constexpr int ITERS   = 50;
constexpr int KP      = OUT_DIM / 2;   // 5 k-pairs

constexpr float DT = 0.05f, LBD1 = 0.005f, LBD2 = 0.005f;

// ---------------- setup: build packed table in d_ws ----------------
// ws layout (uint32 words): [0..49]  Gp[m][j] as h2  (m-pair-major: m*10+j)
//                           [50..59] rd[j] as f32
__global__ void pcn_setup(const float* __restrict__ Mg, uint32_t* __restrict__ ws) {
    int t = threadIdx.x;
    if (t < 50) {
        int m = t / OUT_DIM, j = t % OUT_DIM;
        int k0 = 2 * m, k1 = 2 * m + 1;
        float rdj  = 1.0f / (LBD2 + Mg[j  * OUT_DIM + j]);
        float rdk0 = 1.0f / (LBD2 + Mg[k0 * OUT_DIM + k0]);
        float rdk1 = 1.0f / (LBD2 + Mg[k1 * OUT_DIM + k1]);
        float g0 = (k0 == j) ? (1.0f - DT) * rdj : -DT * rdk0 * Mg[k0 * OUT_DIM + j];
        float g1 = (k1 == j) ? (1.0f - DT) * rdj : -DT * rdk1 * Mg[k1 * OUT_DIM + j];
        h2 p; p.x = (_Float16)g0; p.y = (_Float16)g1;
        ws[t] = __builtin_bit_cast(uint32_t, p);
    }
    if (t < OUT_DIM) {
        float rd = 1.0f / (LBD2 + Mg[t * OUT_DIM + t]);
        ws[50 + t] = __builtin_bit_cast(uint32_t, rd);
    }
}

// ---------------- main ----------------
__global__ __launch_bounds__(256) void pcn_kernel(
    const float* __restrict__ X,        // [n, 5]
    const float* __restrict__ W,        // [10, 5]
    const float* __restrict__ b,        // [10]
    const uint32_t* __restrict__ ws,    // packed table (read-only here)
    float* __restrict__ out,            // [n, 10]
    int n)
{
    int i = blockIdx.x * blockDim.x + threadIdx.x;
    if (i >= n) return;

    // Uniform table -> SGPRs (s_load; resident, never remat'ed)
    uint32_t g[KP][OUT_DIM];
#pragma unroll
    for (int m = 0; m < KP; ++m)
#pragma unroll
        for (int j = 0; j < OUT_DIM; ++j)
            g[m][j] = ws[m * OUT_DIM + j];
    float rd[OUT_DIM];
#pragma unroll
    for (int j = 0; j < OUT_DIM; ++j)
        rd[j] = __builtin_bit_cast(float, ws[50 + j]);

    // per-row constant c (f32; W/b come in as s_loads)
    float x[IN_DIM];
#pragma unroll
    for (int d = 0; d < IN_DIM; ++d) x[d] = X[(size_t)i * IN_DIM + d];
    float c[OUT_DIM];
#pragma unroll
    for (int j = 0; j < OUT_DIM; ++j) {
        float s = -b[j];
#pragma unroll
        for (int d = 0; d < IN_DIM; ++d)
            s = fmaf(x[d], W[j * IN_DIM + d], s);
        c[j] = fmaf(DT, s, -LBD1);
    }

    // 50 iterations, ping-pong packed f16 state, f32 accumulation
    h2 za[KP], zb[KP];
#pragma unroll
    for (int m = 0; m < KP; ++m) { za[m].x = (_Float16)0; za[m].y = (_Float16)0; }

    auto step = [&](const h2* zi, h2* zo) {
#pragma unroll
        for (int jp = 0; jp < KP; ++jp) {
            float a0 = c[2 * jp], a1 = c[2 * jp + 1];
#pragma unroll
            for (int m = 0; m < KP; ++m) {
                a0 = __builtin_amdgcn_fdot2(zi[m], __builtin_bit_cast(h2, g[m][2 * jp]),     a0, false);
                a1 = __builtin_amdgcn_fdot2(zi[m], __builtin_bit_cast(h2, g[m][2 * jp + 1]), a1, false);
            }
            h2 t; t.x = (_Float16)a0; t.y = (_Float16)a1;   // cvt x2 + pack
            h2 zero; zero.x = (_Float16)0; zero.y = (_Float16)0;
            zo[jp] = __builtin_elementwise_max(t, zero);    // v_pk_max_f16
        }
    };

#pragma unroll 1
    for (int it = 0; it < ITERS / 2; ++it) {
        step(za, zb);
        step(zb, za);
    }

    // epilogue: Y = rd .* z
#pragma unroll
    for (int m = 0; m < KP; ++m) {
        out[(size_t)i * OUT_DIM + 2 * m]     = rd[2 * m]     * (float)za[m].x;
        out[(size_t)i * OUT_DIM + 2 * m + 1] = rd[2 * m + 1] * (float)za[m].y;
    }
}

// ---------------- fallback (ws too small): R6-style self-contained ----------------
__global__ __launch_bounds__(256) void pcn_kernel_fb(
    const float* __restrict__ X, const float* __restrict__ W,
    const float* __restrict__ Mg, const float* __restrict__ b,
    float* __restrict__ out, int n)
{
    int i = blockIdx.x * blockDim.x + threadIdx.x;
    if (i >= n) return;
    float rd[OUT_DIM];
#pragma unroll
    for (int j = 0; j < OUT_DIM; ++j) rd[j] = 1.0f / (LBD2 + Mg[j * OUT_DIM + j]);
    h2 Gp[KP][OUT_DIM];
#pragma unroll
    for (int m = 0; m < KP; ++m)
#pragma unroll
        for (int j = 0; j < OUT_DIM; ++j) {
            int k0 = 2 * m, k1 = 2 * m + 1;
            float g0 = (k0 == j) ? (1.0f - DT) * rd[j] : -DT * rd[k0] * Mg[k0 * OUT_DIM + j];
            float g1 = (k1 == j) ? (1.0f - DT) * rd[j] : -DT * rd[k1] * Mg[k1 * OUT_DIM + j];
            Gp[m][j].x = (_Float16)g0; Gp[m][j].y = (_Float16)g1;
        }
    float x[IN_DIM];
#pragma unroll
    for (int d = 0; d < IN_DIM; ++d) x[d] = X[(size_t)i * IN_DIM + d];
    float c[OUT_DIM];
#pragma unroll
    for (int j = 0; j < OUT_DIM; ++j) {
        float s = -b[j];
#pragma unroll
        for (int d = 0; d < IN_DIM; ++d) s = fmaf(x[d], W[j * IN_DIM + d], s);
        c[j] = fmaf(DT, s, -LBD1);
    }
    h2 zp[KP];
#pragma unroll
    for (int m = 0; m < KP; ++m) { zp[m].x = (_Float16)0; zp[m].y = (_Float16)0; }
#pragma unroll 1
    for (int it = 0; it < ITERS; ++it) {
        float s[OUT_DIM];
#pragma unroll
        for (int j = 0; j < OUT_DIM; ++j) {
            float acc = c[j];
#pragma unroll
            for (int m = 0; m < KP; ++m)
                acc = __builtin_amdgcn_fdot2(zp[m], Gp[m][j], acc, false);
            s[j] = fmaxf(acc, 0.0f);
        }
#pragma unroll
        for (int m = 0; m < KP; ++m) { zp[m].x = (_Float16)s[2*m]; zp[m].y = (_Float16)s[2*m+1]; }
    }
#pragma unroll
    for (int m = 0; m < KP; ++m) {
        out[(size_t)i * OUT_DIM + 2 * m]     = rd[2 * m]     * (float)zp[m].x;
        out[(size_t)i * OUT_DIM + 2 * m + 1] = rd[2 * m + 1] * (float)zp[m].y;
    }
}

extern "C" void kernel_launch(void* const* d_in, const int* in_sizes, int n_in,
                              void* d_out, int out_size, void* d_ws, size_t ws_size,
                              hipStream_t stream) {
    const float* X = (const float*)d_in[0];
    const float* W = (const float*)d_in[1];
    const float* M = (const float*)d_in[2];
    const float* b = (const float*)d_in[3];
    float* out = (float*)d_out;

    int n = in_sizes[0] / IN_DIM;   // 500000 rows
    int block = 256;
    int grid = (n + block - 1) / block;

    if (ws_size >= 256) {
        pcn_setup<<<1, 64, 0, stream>>>(M, (uint32_t*)d_ws);
        pcn_kernel<<<grid, block, 0, stream>>>(X, W, b, (const uint32_t*)d_ws, out, n);
    } else {
        pcn_kernel_fb<<<grid, block, 0, stream>>>(X, W, M, b, out, n);
    }
}

// Round 8
// 111.736 us; speedup vs baseline: 1.1083x; 1.0912x over previous
//
#include <hip/hip_runtime.h>
#include <stdint.h>

// PlaceCellNetwork — 50 fixed-point Jacobi iterations, per-row independent.
//
// R8: row-pair f16 packing + LDS-staged coefficient table.
//
// Evidence so far:
//  - R3/R5/R6: VALU-computed uniform tables get REMATERIALIZED in-loop
//    (VGPR_Count 72/72/44) — 2x instr bloat. asm pins don't stick.
//  - R4/R7: SGPR placement fails — 90-100 words overflow the ~100-SGPR file
//    (R4), and VOP3P+SGPR operand doesn't fold cleanly (R7: 5.95 cyc/row-iter
//    vs 1.7 floor).
//  - Fix: table values become ds_read RESULTS (loads are not remattable),
//    per-lane VGPRs, ~140 live regs -> 3 waves/SIMD.
//
// Packing: thread owns 2 rows; state z[k] is h2=(row0,row1). Coefficient
// G[k][j] is scalar for both halves -> duplicated into both f16 halves at
// table-build time. Inner: 100 v_pk_fma_f16 + 10 v_pk_max_f16 per iter per
// 2 rows = 55 inst/row-iter, all full-rate VGPR-only VOP3P.
// Floor: 110*2cyc*50 * 3906 waves / 1024 SIMD ~= 18 us.
//
// Precision: f16 accumulate, but summation ordered small-first: off-diag
// terms (~0.01, since M_offdiag = 0.01*noise) onto c (~0.5) first, dominant
// diagonal G_jj*z_j added LAST -> one f16 rounding at |s|~10 per output/iter.
// Steady-state ~0.05 + measured 0.0625 state-quant (R6/R7) -> ~0.1 absmax
// expected vs 0.318 threshold.
//
// z-space recurrence (identical to R6/R7, which passed at 0.0625):
//   z_j <- max( sum_k G[k][j]*z_k + c_j , 0 )
//   G[j][j] = (1-dt)*rd_j ; G[k][j] = -dt*rd_k*M_kj ; rd_j = 1/(lbd2+M_jj)
//   c_j = dt*(Wx_j - b_j) - lbd1 ;  Y_j = rd_j * z_j

typedef _Float16 h2 __attribute__((ext_vector_type(2)));

constexpr int IN_DIM  = 5;
constexpr int OUT_DIM = 10;
constexpr int ITERS   = 50;

constexpr float DT = 0.05f, LBD1 = 0.005f, LBD2 = 0.005f;

__global__ __launch_bounds__(256) void pcn_kernel(
    const float* __restrict__ X,    // [n, 5]
    const float* __restrict__ W,    // [10, 5]
    const float* __restrict__ Mg,   // [10, 10]
    const float* __restrict__ b,    // [10]
    float* __restrict__ out,        // [n, 10]
    int npairs)                     // n/2
{
    // ---- per-block table build in LDS ----
    // tbl[k*10+j]  : h2{g,g} (f16 G[k][j] duplicated in both halves)
    // tbl[100+j]   : f32 rd[j]
    __shared__ uint32_t tbl[112];
    int tid = threadIdx.x;
    if (tid < 100) {
        int k = tid / OUT_DIM, j = tid % OUT_DIM;
        float rdk = 1.0f / (LBD2 + Mg[k * OUT_DIM + k]);
        float rdj = 1.0f / (LBD2 + Mg[j * OUT_DIM + j]);
        float g = (k == j) ? (1.0f - DT) * rdj
                           : -DT * rdk * Mg[k * OUT_DIM + j];
        h2 p; p.x = (_Float16)g; p.y = (_Float16)g;
        tbl[tid] = __builtin_bit_cast(uint32_t, p);
    }
    if (tid < OUT_DIM) {
        tbl[100 + tid] = __builtin_bit_cast(uint32_t,
                            1.0f / (LBD2 + Mg[tid * OUT_DIM + tid]));
    }
    __syncthreads();

    int t = blockIdx.x * blockDim.x + tid;
    if (t >= npairs) return;

    // ---- table -> per-lane VGPRs (ds_read results: cannot be remat'ed) ----
    h2 G[OUT_DIM][OUT_DIM];
#pragma unroll
    for (int k = 0; k < OUT_DIM; ++k)
#pragma unroll
        for (int j = 0; j < OUT_DIM; ++j)
            G[k][j] = __builtin_bit_cast(h2, tbl[k * OUT_DIM + j]);

    // ---- per-row-pair constant c (f32 math, packed to h2) ----
    const float* xp = X + (size_t)t * (2 * IN_DIM);
    float x0[IN_DIM], x1[IN_DIM];
#pragma unroll
    for (int d = 0; d < IN_DIM; ++d) { x0[d] = xp[d]; x1[d] = xp[IN_DIM + d]; }
    h2 c[OUT_DIM];
#pragma unroll
    for (int j = 0; j < OUT_DIM; ++j) {
        float s0 = -b[j], s1 = -b[j];
#pragma unroll
        for (int d = 0; d < IN_DIM; ++d) {
            float w = W[j * IN_DIM + d];
            s0 = fmaf(x0[d], w, s0);
            s1 = fmaf(x1[d], w, s1);
        }
        c[j].x = (_Float16)fmaf(DT, s0, -LBD1);
        c[j].y = (_Float16)fmaf(DT, s1, -LBD1);
    }

    // ---- 50 iterations, ping-pong; 110 pk insts per iter per 2 rows ----
    h2 z[OUT_DIM], zn[OUT_DIM];
#pragma unroll
    for (int j = 0; j < OUT_DIM; ++j) { z[j].x = (_Float16)0; z[j].y = (_Float16)0; }

    h2 zero; zero.x = (_Float16)0; zero.y = (_Float16)0;

    auto step = [&](const h2* zi, h2* zo) {
#pragma unroll
        for (int j = 0; j < OUT_DIM; ++j) {
            // small off-diagonal terms first (onto c ~0.5), diagonal LAST
            h2 acc = c[j];
#pragma unroll
            for (int k = 0; k < OUT_DIM; ++k)
                if (k != j)
                    acc = __builtin_elementwise_fma(G[k][j], zi[k], acc);
            acc = __builtin_elementwise_fma(G[j][j], zi[j], acc);
            zo[j] = __builtin_elementwise_max(acc, zero);
        }
    };

#pragma unroll 1
    for (int it = 0; it < ITERS / 2; ++it) {
        step(z, zn);
        step(zn, z);
    }

    // ---- epilogue: Y = rd .* z, 2 rows = 20 contiguous floats ----
    float* o = out + (size_t)t * (2 * OUT_DIM);
    float y0[OUT_DIM], y1[OUT_DIM];
#pragma unroll
    for (int j = 0; j < OUT_DIM; ++j) {
        float rdj = __builtin_bit_cast(float, tbl[100 + j]);
        y0[j] = rdj * (float)z[j].x;
        y1[j] = rdj * (float)z[j].y;
    }
#pragma unroll
    for (int j = 0; j < OUT_DIM; ++j) {
        o[j] = y0[j];
        o[OUT_DIM + j] = y1[j];
    }
}

extern "C" void kernel_launch(void* const* d_in, const int* in_sizes, int n_in,
                              void* d_out, int out_size, void* d_ws, size_t ws_size,
                              hipStream_t stream) {
    const float* X = (const float*)d_in[0];
    const float* W = (const float*)d_in[1];
    const float* M = (const float*)d_in[2];
    const float* b = (const float*)d_in[3];
    float* out = (float*)d_out;

    int n = in_sizes[0] / IN_DIM;   // 500000 rows (even)
    int npairs = n / 2;
    int block = 256;
    int grid = (npairs + block - 1) / block;
    pcn_kernel<<<grid, block, 0, stream>>>(X, W, M, b, out, npairs);
}

// Round 11
// 97.333 us; speedup vs baseline: 1.2723x; 1.1480x over previous
//
#include <hip/hip_runtime.h>
#include <stdint.h>

// PlaceCellNetwork — 50 fixed-point Jacobi iterations, per-row independent.
//
// R11 = R10 with the HOST-pass compile fixed. R10 evidence: device pass
// (gfx950) compiled clean — __builtin_amdgcn_mfma_f32_16x16x16f16 exists on
// device and accepts _Float16 vectors; only the host pass lacks the builtin
// (__has_builtin false on x86 -> my #error fired). Host never executes
// device code, so it gets a parse-only stub.
//
// Theory (unchanged):
// z' = relu(G^T z + c) IS a 16x16x16 f16 matmul:
//   M = output j (10 of 16), N = batch rows (16/tile), K = state k (10 of 16).
// The whole 10x10 G matrix is ONE mfma A-fragment = 2 VGPRs/lane — the
// table-residency problem (R3..R8: remat / SGPR overflow / LDS re-reads)
// disappears by construction.
//
// Layout (guide §3, m89/m91 family): for 16x16x16_f16,
//   A[m][k]: lane = m + 16*(k/4),  elem = k%4
//   B[k][n]: lane = n + 16*(k/4),  elem = k%4
//   D[m][n]: lane = n + 16*(m/4),  elem = m%4
// => D's (lane,elem) mapping is IDENTICAL to B's, so D -> cvt f16 -> relu ->
// next B needs ZERO cross-lane movement. c rides as the C operand. A rows
// m>=10 and c entries j>=10 zeroed => padded region of D stays exactly 0.
//
// Per wave: 4 independent 16-row tiles. Per iter per tile: 1 mfma + 2
// cvt_pkrtz + 2 v_pk_max_f16 (on the f16 pairs). Numerics: f16 state/G but
// f32 MFMA accumulate — strictly better than R8 (passed at absmax 0.0625).

typedef _Float16 h2 __attribute__((ext_vector_type(2)));
typedef _Float16 h4 __attribute__((ext_vector_type(4)));
typedef float    f4 __attribute__((ext_vector_type(4)));

constexpr int IN_DIM  = 5;
constexpr int OUT_DIM = 10;
constexpr int ITERS   = 50;
constexpr float DT = 0.05f, LBD1 = 0.005f, LBD2 = 0.005f;

#if defined(__HIP_DEVICE_COMPILE__)
  // Device pass: builtin verified present on gfx950 (R10 device pass clean).
  #define MFMA16(a, b, c) __builtin_amdgcn_mfma_f32_16x16x16f16((a), (b), (c), 0, 0, 0)
#else
  // Host pass: never executed, just needs to parse/typecheck.
  #define MFMA16(a, b, c) (c)
#endif

__device__ __forceinline__ h2 cvt_pk(float a, float b) {
    // v_cvt_pkrtz_f16_f32; builtin returns __fp16 ext_vector(2) -> bit_cast
    return __builtin_bit_cast(h2, __builtin_amdgcn_cvt_pkrtz(a, b));
}

__global__ __launch_bounds__(256) void pcn_kernel(
    const float* __restrict__ X,    // [n, 5]
    const float* __restrict__ W,    // [10, 5]
    const float* __restrict__ Mg,   // [10, 10]
    const float* __restrict__ b,    // [10]
    float* __restrict__ out,        // [n, 10]
    int n)
{
    // ---- build G (f32) + rd in LDS, once per block ----
    __shared__ float gtab[100];     // G[k][j] = (k==j)?(1-dt)*rd_j : -dt*rd_k*M_kj
    __shared__ float rdtab[OUT_DIM];
    int tid = threadIdx.x;
    if (tid < 100) {
        int k = tid / 10, j = tid % 10;
        float rdk = 1.0f / (LBD2 + Mg[k * 10 + k]);
        float rdj = 1.0f / (LBD2 + Mg[j * 10 + j]);
        gtab[tid] = (k == j) ? (1.0f - DT) * rdj : -DT * rdk * Mg[k * 10 + j];
        if (tid < OUT_DIM) rdtab[tid] = rdj;    // k==0 here, j==tid
    }
    __syncthreads();

    const int lane = tid & 63;
    const int w    = tid >> 6;      // wave in block (0..3)
    const int grp  = lane >> 4;     // element group (0..3)
    const int r16  = lane & 15;     // N-index (row within tile)

    // ---- A fragment: A[m][k] = G[k][m]; lane holds m=r16, k=grp*4+e ----
    h4 afrag;
#pragma unroll
    for (int e = 0; e < 4; ++e) {
        int k = grp * 4 + e;
        float g = (k < OUT_DIM && r16 < OUT_DIM) ? gtab[k * 10 + r16] : 0.0f;
        afrag[e] = (_Float16)g;
    }

    // ---- per-lane j-set data (m = grp*4+e in C/D layout) ----
    float rdv[4], Wj[4][IN_DIM], bj[4];
#pragma unroll
    for (int e = 0; e < 4; ++e) {
        int j = grp * 4 + e;
        if (j < OUT_DIM) {
            rdv[e] = rdtab[j];
            bj[e]  = b[j];
#pragma unroll
            for (int d = 0; d < IN_DIM; ++d) Wj[e][d] = W[j * IN_DIM + d];
        } else {
            rdv[e] = 0.0f; bj[e] = 0.0f;
#pragma unroll
            for (int d = 0; d < IN_DIM; ++d) Wj[e][d] = 0.0f;
        }
    }

    // ---- per-tile c fragments (C-operand) ----
    const long base = (long)blockIdx.x * 256 + (long)w * 64;
    f4 cf[4];
#pragma unroll
    for (int t = 0; t < 4; ++t) {
        long r = base + t * 16 + r16;
        float x[IN_DIM];
        if (r < n) {
#pragma unroll
            for (int d = 0; d < IN_DIM; ++d) x[d] = X[r * IN_DIM + d];
        } else {
#pragma unroll
            for (int d = 0; d < IN_DIM; ++d) x[d] = 0.0f;
        }
#pragma unroll
        for (int e = 0; e < 4; ++e) {
            int j = grp * 4 + e;
            if (j < OUT_DIM) {
                float s = -bj[e];
#pragma unroll
                for (int d = 0; d < IN_DIM; ++d) s = fmaf(x[d], Wj[e][d], s);
                cf[t][e] = fmaf(DT, s, -LBD1);
            } else {
                cf[t][e] = 0.0f;    // keeps padded D rows exactly 0
            }
        }
    }

    // ---- iterate: B_{t+1} = pk_max(cvt(mfma(A, B_t, c)), 0) ----
    h4 B[4];
#pragma unroll
    for (int t = 0; t < 4; ++t)
#pragma unroll
        for (int e = 0; e < 4; ++e) B[t][e] = (_Float16)0.0f;

    h2 zero2; zero2.x = (_Float16)0.0f; zero2.y = (_Float16)0.0f;

#pragma unroll 1
    for (int it = 0; it < ITERS - 1; ++it) {
#pragma unroll
        for (int t = 0; t < 4; ++t) {
            f4 acc = MFMA16(afrag, B[t], cf[t]);
            h2 lo = cvt_pk(acc[0], acc[1]);
            h2 hi = cvt_pk(acc[2], acc[3]);
            lo = __builtin_elementwise_max(lo, zero2);   // v_pk_max_f16
            hi = __builtin_elementwise_max(hi, zero2);
            B[t][0] = lo.x; B[t][1] = lo.y; B[t][2] = hi.x; B[t][3] = hi.y;
        }
    }

    // ---- final iteration in f32 + scaled store: Y[r][j] = rd_j * z_j ----
#pragma unroll
    for (int t = 0; t < 4; ++t) {
        f4 acc = MFMA16(afrag, B[t], cf[t]);
        long r = base + t * 16 + r16;
        if (r < n) {
            float y0 = fmaxf(acc[0], 0.0f) * rdv[0];
            float y1 = fmaxf(acc[1], 0.0f) * rdv[1];
            float y2 = fmaxf(acc[2], 0.0f) * rdv[2];
            float y3 = fmaxf(acc[3], 0.0f) * rdv[3];
            float* o = out + r * OUT_DIM + grp * 4;
            if (grp < 2) {                    // j 0-3 / 4-7: two 8B stores
                *(float2*)(o)     = make_float2(y0, y1);
                *(float2*)(o + 2) = make_float2(y2, y3);
            } else if (grp == 2) {            // j 8-9
                *(float2*)(o)     = make_float2(y0, y1);
            }                                  // grp==3: j>=12, nothing
        }
    }
}

extern "C" void kernel_launch(void* const* d_in, const int* in_sizes, int n_in,
                              void* d_out, int out_size, void* d_ws, size_t ws_size,
                              hipStream_t stream) {
    const float* X = (const float*)d_in[0];
    const float* W = (const float*)d_in[1];
    const float* M = (const float*)d_in[2];
    const float* b = (const float*)d_in[3];
    float* out = (float*)d_out;

    int n = in_sizes[0] / IN_DIM;           // 500000 rows
    int rows_per_block = 256;               // 4 waves x 4 tiles x 16 rows
    int grid = (n + rows_per_block - 1) / rows_per_block;
    pcn_kernel<<<grid, 256, 0, stream>>>(X, W, M, b, out, n);
}